// Round 1
// 5806.886 us; speedup vs baseline: 1.4272x; 1.4272x over previous
//
#include <hip/hip_runtime.h>
#include <stdint.h>

#define T_STEPS 512
#define NB 64
#define NI 512
#define NH 1024
#define NBLK 128
// gate-cols total = 4*NH = 4096

typedef __attribute__((ext_vector_type(8))) short short8;
typedef __attribute__((ext_vector_type(4))) float floatx4;
typedef __attribute__((ext_vector_type(16))) float floatx16;
typedef __attribute__((ext_vector_type(4))) unsigned short ushortx4;

__device__ __forceinline__ unsigned short f2bf(float f) {
  union { float f; uint32_t u; } v; v.f = f;
  return (unsigned short)((v.u + 0x7FFFu + ((v.u >> 16) & 1u)) >> 16);
}
__device__ __forceinline__ float bf2f(unsigned short s) {
  union { uint32_t u; float f; } v; v.u = ((uint32_t)s) << 16; return v.f;
}
__device__ __forceinline__ float sigmoid_f(float x) {
  return 1.0f / (1.0f + __expf(-x));
}
__device__ __forceinline__ float tanh_f(float x) {
  float xx = fminf(fmaxf(x, -15.0f), 15.0f);
  float e = __expf(2.0f * xx);
  return (e - 1.0f) / (e + 1.0f);
}

// ---------------- prep kernels ----------------

// X fp32 [T*B*I] -> bf16, 4 elems/thread, exact grid
__global__ void convert_x(const float* __restrict__ X, unsigned short* __restrict__ Xb) {
  int i = blockIdx.x * 256 + threadIdx.x;
  floatx4 x = ((const floatx4*)X)[i];
  ushortx4 o;
  o[0] = f2bf(x[0]); o[1] = f2bf(x[1]); o[2] = f2bf(x[2]); o[3] = f2bf(x[3]);
  ((ushortx4*)Xb)[i] = o;
}

// in [G][K][N] fp32 -> out [G][N][K] bf16 (n-major so K is contiguous)
__global__ void transpose_bf16(const float* __restrict__ in, unsigned short* __restrict__ outp,
                               int K, int N) {
  __shared__ float tile[64][65];
  int g = blockIdx.z;
  int k0 = blockIdx.x * 64, n0 = blockIdx.y * 64;
  int tx = threadIdx.x & 63, ty = threadIdx.x >> 6;
  const float* src = in + (size_t)g * K * N;
  unsigned short* dst = outp + (size_t)g * K * N;
#pragma unroll
  for (int i = 0; i < 16; i++) {
    int r = ty * 16 + i;
    tile[r][tx] = src[(size_t)(k0 + r) * N + n0 + tx];
  }
  __syncthreads();
#pragma unroll
  for (int i = 0; i < 16; i++) {
    int r = ty * 16 + i;
    dst[(size_t)(n0 + r) * K + k0 + tx] = f2bf(tile[tx][r]);
  }
}

// bias = bi + bh (fp32), hbuf0 = bf16(h0), zero barrier flags (packed, 128 dwords)
__global__ void prep_small(const float* __restrict__ bi, const float* __restrict__ bh,
                           const float* __restrict__ h0, float* __restrict__ bias,
                           unsigned short* __restrict__ hbuf0, unsigned* __restrict__ flags) {
  int i = blockIdx.x * 256 + threadIdx.x;
  if (i < NBLK) flags[i] = 0u;   // packed flags for dwordx2 polling
  if (i < 4 * NH) bias[i] = bi[i] + bh[i];
  if (i < NB * NH) hbuf0[i] = f2bf(h0[i]);
}

// ---------------- Zx GEMM: Zx[m][g*NH+n] = sum_k Xb[m][k]*WibT[g][n][k] + bias ----------------
__global__ __launch_bounds__(256) void gemm_zx(
    const unsigned short* __restrict__ Xb,
    const unsigned short* __restrict__ WibT,
    const float* __restrict__ bias,
    unsigned short* __restrict__ Zx) {
  __shared__ __align__(16) unsigned short As[128][40];  // +8 pad
  __shared__ __align__(16) unsigned short Bs[128][40];
  const int g = blockIdx.z;
  const int m0 = blockIdx.x * 128;
  const int n0 = blockIdx.y * 128;
  const int tid = threadIdx.x;
  const int lane = tid & 63;
  const int wave = tid >> 6;
  const int wm = wave & 1, wn = wave >> 1;
  const int fr = lane & 15;            // frag row (m for A, n for B)
  const int fq = (lane >> 4) * 8;      // frag k offset

  const unsigned short* Bsrc = WibT + (size_t)g * NH * NI;

  floatx4 acc[4][4];
#pragma unroll
  for (int a = 0; a < 4; a++)
#pragma unroll
    for (int b = 0; b < 4; b++)
#pragma unroll
      for (int z = 0; z < 4; z++) acc[a][b][z] = 0.0f;

  for (int k0 = 0; k0 < NI; k0 += 32) {
#pragma unroll
    for (int it = 0; it < 2; it++) {
      int c = tid + it * 256;            // 0..511
      int row = c >> 2, kc = (c & 3) * 8;
      *(uint4*)(&As[row][kc]) = *(const uint4*)(Xb + (size_t)(m0 + row) * NI + k0 + kc);
      *(uint4*)(&Bs[row][kc]) = *(const uint4*)(Bsrc + (size_t)(n0 + row) * NI + k0 + kc);
    }
    __syncthreads();
    short8 af[4], bf[4];
#pragma unroll
    for (int ms = 0; ms < 4; ms++) af[ms] = *(const short8*)(&As[wm * 64 + ms * 16 + fr][fq]);
#pragma unroll
    for (int ns = 0; ns < 4; ns++) bf[ns] = *(const short8*)(&Bs[wn * 64 + ns * 16 + fr][fq]);
#pragma unroll
    for (int ms = 0; ms < 4; ms++)
#pragma unroll
      for (int ns = 0; ns < 4; ns++)
        acc[ms][ns] = __builtin_amdgcn_mfma_f32_16x16x32_bf16(af[ms], bf[ns], acc[ms][ns], 0, 0, 0);
    __syncthreads();
  }

  // C/D layout (16x16, verified): col = lane&15, row = (lane>>4)*4 + reg
#pragma unroll
  for (int ns = 0; ns < 4; ns++) {
    int col = n0 + wn * 64 + ns * 16 + fr;
    float bs = bias[g * NH + col];
#pragma unroll
    for (int ms = 0; ms < 4; ms++) {
#pragma unroll
      for (int r = 0; r < 4; r++) {
        int m = m0 + wm * 64 + ms * 16 + (lane >> 4) * 4 + r;
        Zx[(size_t)m * 4096 + (size_t)g * NH + col] = f2bf(acc[ms][ns][r] + bs);
      }
    }
  }
}

// ---------------- persistent recurrent kernel ----------------
// R4 changes vs R3 (15.3 us/step):
//  * no buffer_inv: h read with agent-scope bypass loads (global_load_dwordx4 sc0 sc1).
//    R3's per-block inv nuked the SHARED per-XCD L2 16x/XCD/step, so h never served
//    from L2 anyway; bypass removes the inv cost + cross-block interference.
//  * explicit 16-deep rolling A-load window with counted s_waitcnt vmcnt(N): R3's
//    post-inv A-loads were ~16 serialized LLC miss-rounds (~4 us/step exposed).
//    Data dep on waited reg via "+v" tie (compiler can't hoist MFMA past the wait).
//  * arrive moved to TOP of step (spin on 128 packed flags >= t); Zx prefetch moved
//    AFTER the flag post so release vmcnt(0) drains only h/out stores and Zx latency
//    hides under the spin.
//  WAW-safety without inv: block passing spin(t) => all flags >= t => every block
//  finished reading h_{t-1} before this block's h_{t+1} stores overwrite that slot.
__device__ __forceinline__ void issue_none() {}

template<int G>
__device__ __forceinline__ void load_a(const unsigned short* ap, short8 (&areg)[64]) {
  asm volatile("global_load_dwordx4 %0, %1, off offset:%2 sc0 sc1"
               : "=v"(areg[G]) : "v"(ap), "i"(G * 32));
}

template<int G>
__device__ __forceinline__ void load_b(const unsigned short* bfr, int lane, short8 (&bs)[64]) {
  bs[G] = *(const short8*)(&bfr[((size_t)(G * 64) + lane) * 8]);
}

template<int G>
struct Prolog {
  static __device__ __forceinline__ void run(const unsigned short* ap, short8 (&areg)[64]) {
    load_a<G>(ap, areg);
    Prolog<G + 1>::run(ap, areg);
  }
};
template<>
struct Prolog<16> {
  static __device__ __forceinline__ void run(const unsigned short*, short8 (&)[64]) {}
};

template<int G>
struct Chunks {
  static __device__ __forceinline__ void run(const unsigned short* ap, const unsigned short* bfr,
                                             int lane, short8 (&areg)[64], short8 (&bs)[64],
                                             floatx16& acc0, floatx16& acc1) {
    if constexpr (G + 16 < 64) load_a<G + 16>(ap, areg);      // keep 16 in flight
    if constexpr (G + 4 < 64) load_b<G + 4>(bfr, lane, bs);   // B frag 4 ahead (ds)
    constexpr int NOUT = (G + 16 < 64) ? 16 : (63 - G);
    // wait chunk G; "+v" tie makes the MFMA data-dependent on this asm (rule #18),
    // "memory" pins later Zx/epilogue vmem below the counted region.
    asm volatile("s_waitcnt vmcnt(%1)" : "+v"(areg[G]) : "i"(NOUT) : "memory");
    if constexpr ((G & 1) == 0)
      acc0 = __builtin_amdgcn_mfma_f32_32x32x16_bf16(areg[G], bs[G], acc0, 0, 0, 0);
    else
      acc1 = __builtin_amdgcn_mfma_f32_32x32x16_bf16(areg[G], bs[G], acc1, 0, 0, 0);
    Chunks<G + 1>::run(ap, bfr, lane, areg, bs, acc0, acc1);
  }
};
template<>
struct Chunks<64> {
  static __device__ __forceinline__ void run(const unsigned short*, const unsigned short*,
                                             int, short8 (&)[64], short8 (&)[64],
                                             floatx16&, floatx16&) {}
};

__global__ __launch_bounds__(128, 1) void lstm_persist(
    const unsigned short* __restrict__ Zx,
    const unsigned short* __restrict__ WhT,   // [4][NH(n)][NH(k)] bf16
    const float* __restrict__ c0,
    unsigned short* __restrict__ hbuf,        // 2 x NB x NH bf16
    unsigned* __restrict__ flags,             // NBLK packed dwords
    float* __restrict__ out) {
  __shared__ __align__(16) unsigned short bfr[64 * 64 * 8];  // [kk][lane][8] = 64 KB

  const int bk = blockIdx.x;
  const int j0 = bk * 8;
  const int tid = threadIdx.x;
  const int lane = tid & 63;
  const int wm = tid >> 6;        // wave = batch half (m-tile of 32)
  const int nl = lane & 31;       // MFMA col n (0..31): gate g0 = n>>3, h-col jj = n&7
  const int g0 = nl >> 3;
  const int jj = nl & 7;
  const int half = lane >> 5;

  // Fill B fragments: B[k][n] = Wh[g][k][j0+jj] = WhT[g][j0+jj][k]
  for (int i = 0; i < 32; i++) {
    int f = tid + i * 128;        // 0..4095 = kk*64 + lane
    int fl = f & 63, kk = f >> 6;
    int n = fl & 31;
    size_t wrow = (size_t)((n >> 3) * NH + j0 + (n & 7));
    int kb = kk * 16 + (fl >> 5) * 8;
    uint4 v = *(const uint4*)(WhT + wrow * NH + kb);
    *(uint4*)(&bfr[(size_t)f * 8]) = v;
  }

  // c state in C/D layout: row = (r&3) + 8*(r>>2) + 4*half  (rows within 32-tile)
  float creg[16];
  int brow[16];
#pragma unroll
  for (int r = 0; r < 16; r++) {
    brow[r] = wm * 32 + (r & 3) + 8 * (r >> 2) + 4 * half;
    creg[r] = c0[(size_t)brow[r] * NH + j0 + jj];
  }
  __syncthreads();

  const int hsz = NB * NH;

  // Zx prefetch for t=0 (own gate g0 only; quad exchange brings the rest)
  float zx[16];
  {
    const unsigned short* zbase = Zx + (size_t)g0 * NH + j0 + jj;
#pragma unroll
    for (int r = 0; r < 16; r++) zx[r] = bf2f(zbase[(size_t)brow[r] * 4096]);
  }

  for (int t = 0; t < T_STEPS; t++) {
    // ---- arrive: all 128 flags >= t (packed; 2 dwords/lane, agent-scope) ----
    if (t) {
      unsigned tgt = (unsigned)t;
      for (;;) {
        unsigned a = __hip_atomic_load(flags + 2 * lane, __ATOMIC_RELAXED,
                                       __HIP_MEMORY_SCOPE_AGENT);
        unsigned b = __hip_atomic_load(flags + 2 * lane + 1, __ATOMIC_RELAXED,
                                       __HIP_MEMORY_SCOPE_AGENT);
        if (__all((int)(a >= tgt && b >= tgt))) break;
        __builtin_amdgcn_s_sleep(1);
      }
    }
    // clean vmcnt domain before the counted A-load window (drains Zx prefetch too)
    asm volatile("s_waitcnt vmcnt(0)" ::: "memory");
    __builtin_amdgcn_sched_barrier(0);

    const unsigned short* hin = hbuf + (size_t)(t & 1) * hsz;
    unsigned short* hout = hbuf + (size_t)((t + 1) & 1) * hsz;
    const unsigned short* ap = hin + (size_t)(wm * 32 + nl) * NH + half * 8;

    floatx16 acc0, acc1;
#pragma unroll
    for (int z = 0; z < 16; z++) { acc0[z] = 0.0f; acc1[z] = 0.0f; }

    short8 areg[64];
    short8 bs[64];
    Prolog<0>::run(ap, areg);          // issue A chunks 0..15 (bypass loads)
    load_b<0>(bfr, lane, bs);
    load_b<1>(bfr, lane, bs);
    load_b<2>(bfr, lane, bs);
    load_b<3>(bfr, lane, bs);
    Chunks<0>::run(ap, bfr, lane, areg, bs, acc0, acc1);
    __builtin_amdgcn_sched_barrier(0);

#pragma unroll
    for (int z = 0; z < 16; z++) acc0[z] += acc1[z];

    // epilogue: gather all 4 gates across the quad {l, l^8, l^16, l^24}
#pragma unroll
    for (int r = 0; r < 16; r++) {
      float z0 = acc0[r] + zx[r];          // gate g0
      float z1 = __shfl_xor(z0, 8);        // gate g0^1
      float z2 = __shfl_xor(z0, 16);       // gate g0^2
      float z3 = __shfl_xor(z1, 16);       // gate g0^3
      bool bb0 = (g0 & 1) != 0, bb1 = (g0 & 2) != 0;
      float zf = bb1 ? (bb0 ? z3 : z2) : (bb0 ? z1 : z0);  // zq[g0]
      float zi = bb1 ? (bb0 ? z2 : z3) : (bb0 ? z0 : z1);  // zq[1^g0]
      float zg = bb1 ? (bb0 ? z1 : z0) : (bb0 ? z3 : z2);  // zq[2^g0]
      float zo = bb1 ? (bb0 ? z0 : z1) : (bb0 ? z2 : z3);  // zq[3^g0]
      float fg = sigmoid_f(zf);
      float ig = sigmoid_f(zi);
      float gg = tanh_f(zg);
      float og = sigmoid_f(zo);
      float c = fg * creg[r] + ig * gg;
      creg[r] = c;
      float h = og * tanh_f(c);
      if (g0 == 0) {  // one writer per (b, j) quad
        size_t oidx = (size_t)brow[r] * NH + j0 + jj;
        out[(size_t)t * hsz + oidx] = h;
        // agent-scope write-through: reaches coherence point (LLC)
        __hip_atomic_store(&hout[oidx], f2bf(h), __ATOMIC_RELAXED,
                           __HIP_MEMORY_SCOPE_AGENT);
        if (t == T_STEPS - 1) out[(size_t)T_STEPS * hsz + oidx] = h;  // h_n
      }
    }

    if (t + 1 < T_STEPS) {
      // ---- release: h (+out) stores at coherence point, then post flag ----
      asm volatile("s_waitcnt vmcnt(0)" ::: "memory");
      __syncthreads();                                   // both waves drained
      if (tid == 0)
        __hip_atomic_store(flags + bk, (unsigned)(t + 1),
                           __ATOMIC_RELAXED, __HIP_MEMORY_SCOPE_AGENT);
      // Zx prefetch for t+1 — off the release path; hides under next spin
      const unsigned short* zbase =
          Zx + (size_t)(t + 1) * (NB * 4096) + (size_t)g0 * NH + j0 + jj;
#pragma unroll
      for (int r = 0; r < 16; r++) zx[r] = bf2f(zbase[(size_t)brow[r] * 4096]);
    }
  }

  // c_n
  if (g0 == 0) {
#pragma unroll
    for (int r = 0; r < 16; r++)
      out[(size_t)T_STEPS * NB * NH + NB * NH + (size_t)brow[r] * NH + j0 + jj] = creg[r];
  }
}

// ---------------- host launcher ----------------
extern "C" void kernel_launch(void* const* d_in, const int* in_sizes, int n_in,
                              void* d_out, int out_size, void* d_ws, size_t ws_size,
                              hipStream_t stream) {
  const float* X  = (const float*)d_in[0];
  const float* h0 = (const float*)d_in[1];
  const float* c0 = (const float*)d_in[2];
  const float* Wi = (const float*)d_in[3];
  const float* Wh = (const float*)d_in[4];
  const float* bi = (const float*)d_in[5];
  const float* bh = (const float*)d_in[6];
  float* out = (float*)d_out;

  uint8_t* ws = (uint8_t*)d_ws;
  size_t off = 0;
  auto alloc = [&](size_t bytes) -> void* {
    void* p = ws + off;
    off += (bytes + 255) & ~(size_t)255;
    return p;
  };
  unsigned short* Zx   = (unsigned short*)alloc((size_t)T_STEPS * NB * 4096 * 2);  // 268 MB
  unsigned short* Xb   = (unsigned short*)alloc((size_t)T_STEPS * NB * NI * 2);    // 33.6 MB
  unsigned short* WibT = (unsigned short*)alloc((size_t)4 * NH * NI * 2);          // 4.2 MB
  unsigned short* WhT  = (unsigned short*)alloc((size_t)4 * NH * NH * 2);          // 8.4 MB
  float* bias          = (float*)alloc((size_t)4 * NH * 4);
  unsigned short* hbuf = (unsigned short*)alloc((size_t)2 * NB * NH * 2);
  unsigned* flags      = (unsigned*)alloc((size_t)NBLK * 32 * 4);                  // 16 KB (packed: first 512 B used)

  if (off > ws_size) {
    hipMemsetAsync(d_out, 0x7F, (size_t)out_size * 4, stream);
    return;
  }

  convert_x<<<16384, 256, 0, stream>>>(X, Xb);
  transpose_bf16<<<dim3(8, 16, 4), 256, 0, stream>>>(Wi, WibT, NI, NH);
  transpose_bf16<<<dim3(16, 16, 4), 256, 0, stream>>>(Wh, WhT, NH, NH);
  prep_small<<<256, 256, 0, stream>>>(bi, bh, h0, bias, hbuf, flags);
  gemm_zx<<<dim3(256, 8, 4), 256, 0, stream>>>(Xb, WibT, bias, Zx);

  lstm_persist<<<dim3(NBLK), dim3(128), 0, stream>>>(Zx, WhT, c0, hbuf, flags, out);
}